// Round 6
// baseline (421.946 us; speedup 1.0000x reference)
//
#include <hip/hip_runtime.h>

// ---------------------------------------------------------------------------
// CrossAttentionBlockPatched: B=4, Lq=512, Lkv=2048, DIM=1024, H=16, hd=64,
// MLP_HIDDEN=4096, TAU=2.0, EPS=1e-6. fp32 in/out, bf16 MFMA internally.
// ---------------------------------------------------------------------------

typedef __attribute__((ext_vector_type(8))) short short8_t;   // 8 x bf16
typedef __attribute__((ext_vector_type(4))) float f32x4_t;    // 4 x fp32

__device__ __forceinline__ float b2f(short s) {
    union { float f; unsigned u; } c;
    c.u = ((unsigned)(unsigned short)s) << 16;
    return c.f;
}
__device__ __forceinline__ short f2b(float f) {
    union { float f; unsigned u; } c;
    c.f = f;
    unsigned u = c.u;
    unsigned r = (u + 0x7FFFu + ((u >> 16) & 1u)) >> 16;
    return (short)r;
}

// async global -> LDS, 16 B per lane; lds base must be wave-uniform.
__device__ __forceinline__ void gload16(const void* g, void* l) {
    __builtin_amdgcn_global_load_lds(
        (const __attribute__((address_space(1))) void*)g,
        (__attribute__((address_space(3))) void*)l, 16, 0, 0);
}

// ---------------------------------------------------------------------------
// prep: fused q-LN (blocks 0..2047), kv-LN (2048..10239), weight cast
// (10240..22527). LN: fp32 in, bf16 out, one block per 1024-elem row.
// ---------------------------------------------------------------------------
__device__ __forceinline__ void ln_row(
    const float* __restrict__ x, const float* __restrict__ w,
    const float* __restrict__ bia, short* __restrict__ y,
    int row, int tid, float* red)
{
    const float4 t = *(const float4*)(x + (size_t)row * 1024 + tid * 4);
    float v[4] = {t.x, t.y, t.z, t.w};
    float s = v[0] + v[1] + v[2] + v[3];
    float s2 = v[0]*v[0] + v[1]*v[1] + v[2]*v[2] + v[3]*v[3];
    #pragma unroll
    for (int off = 1; off < 64; off <<= 1) {
        s  += __shfl_xor(s, off);
        s2 += __shfl_xor(s2, off);
    }
    const int wave = tid >> 6, lane = tid & 63;
    if (lane == 0) { red[wave] = s; red[4 + wave] = s2; }
    __syncthreads();
    s  = red[0] + red[1] + red[2] + red[3];
    s2 = red[4] + red[5] + red[6] + red[7];
    const float mu  = s * (1.0f / 1024.0f);
    const float var = s2 * (1.0f / 1024.0f) - mu * mu;
    const float rstd = rsqrtf(var + 1e-6f);
    const float4 wv = *(const float4*)(w + tid * 4);
    const float4 bv = *(const float4*)(bia + tid * 4);
    short4 o;
    o.x = f2b((v[0] - mu) * rstd * wv.x + bv.x);
    o.y = f2b((v[1] - mu) * rstd * wv.y + bv.y);
    o.z = f2b((v[2] - mu) * rstd * wv.z + bv.z);
    o.w = f2b((v[3] - mu) * rstd * wv.w + bv.w);
    *(short4*)(y + (size_t)row * 1024 + tid * 4) = o;
}

__global__ __launch_bounds__(256) void prep_kernel(
    const float* __restrict__ qt, const float* __restrict__ kvt,
    const float* __restrict__ qlw, const float* __restrict__ qlb,
    const float* __restrict__ klw, const float* __restrict__ klb,
    short* __restrict__ qn, short* __restrict__ kvn,
    const float* __restrict__ w0, const float* __restrict__ w1,
    const float* __restrict__ w2, const float* __restrict__ w3,
    const float* __restrict__ w4, const float* __restrict__ w5,
    short* __restrict__ o0, short* __restrict__ o1,
    short* __restrict__ o2, short* __restrict__ o3,
    short* __restrict__ o4, short* __restrict__ o5)
{
    __shared__ float red[8];
    const int bid = blockIdx.x, tid = threadIdx.x;
    if (bid < 2048) {
        ln_row(qt, qlw, qlb, qn, bid, tid, red);
    } else if (bid < 10240) {
        ln_row(kvt, klw, klb, kvn, bid - 2048, tid, red);
    } else {
        int f = (bid - 10240) * 256 + tid;   // float4 index, total 3145728
        const float* src; short* dst; int off;
        if (f < 1048576) {
            const int which = f >> 18; off = f & 262143;
            src = which == 0 ? w0 : which == 1 ? w1 : which == 2 ? w2 : w3;
            dst = which == 0 ? o0 : which == 1 ? o1 : which == 2 ? o2 : o3;
        } else {
            f -= 1048576;
            const int which = f >> 20; off = f & 1048575;
            src = which ? w5 : w4; dst = which ? o5 : o4;
        }
        const float4 v = ((const float4*)src)[off];
        short4 o;
        o.x = f2b(v.x); o.y = f2b(v.y); o.z = f2b(v.z); o.w = f2b(v.w);
        ((short4*)dst)[off] = o;
    }
}

// ---------------------------------------------------------------------------
// LayerNorm (standalone, for MLP LN): fp32 in, bf16 out.
// ---------------------------------------------------------------------------
__global__ __launch_bounds__(256) void ln_kernel(
    const float* __restrict__ x, const float* __restrict__ w,
    const float* __restrict__ bia, short* __restrict__ y)
{
    __shared__ float red[8];
    ln_row(x, w, bia, y, blockIdx.x, threadIdx.x, red);
}

// ---------------------------------------------------------------------------
// GEMM: C[M,N] = epilogue(A[M,K] @ W[N,K]^T), bf16 in, BK=64, single-buffered
// LDS, 2 barriers per K-step. 128 B LDS rows, 3-bit XOR swizzle (conflict-free
// ds_read_b128). 4 waves as 2x2 -> wave tile (BM/2)x(BN/2).
// SWZ: 0 = 2D grid (x=n-tile, y=m-tile, z=split-K)
//      1 = KV mapping, 512 1-D blocks: 8 n-tiles(256) x 64 m-tiles(128),
//          same-XCD blocks share an m-band (A stays in one XCD L2)
//      2 = fc1 mapping, 512 blocks: 32 n-tiles x 16 m-tiles (128^2),
//          same-XCD blocks share an n-band (W stays in one XCD L2)
// EPI: 1 outF = resF + alpha*(acc+bias) (fp32)
//      2 gelu_exact(acc+bias) bf16 (fc1)
//      4 l2norm(row, 64-col head) bf16 (q-proj)
//      7 fp32 partial to outF + z*M*N (split-K)
//      8 fused KV: n<1024 -> l2norm + scatter khd[b,h,kv,d] (out16);
//                  n>=1024 -> scatter vhd[b,h,d,kv] ((short*)outF)
// ---------------------------------------------------------------------------
template <int EPI, int BM, int BN, int SWZ>
__global__ __launch_bounds__(256) void gemm_bt_kernel(
    const short* __restrict__ A, const short* __restrict__ W,
    int M, int N, int Ks, int Kst,
    const float* __restrict__ bias,
    const float* __restrict__ resF,
    const float* __restrict__ alpha,
    short* __restrict__ out16,
    float* __restrict__ outF)
{
    constexpr int MI = BM / 32;
    constexpr int NI = BN / 32;
    __shared__ __attribute__((aligned(16))) short As[BM * 64];
    __shared__ __attribute__((aligned(16))) short Bs[BN * 64];
    int bm, bn;
    if (SWZ == 0) {
        bm = blockIdx.y * BM; bn = blockIdx.x * BN;
    } else if (SWZ == 1) {
        const int id = blockIdx.x;
        bn = (id >> 6) * 256;
        bm = (((id & 7) << 3) | ((id >> 3) & 7)) * 128;
    } else {
        const int id = blockIdx.x;
        bn = (((id & 7) << 2) | ((id >> 3) & 3)) * 128;
        bm = (id >> 5) * 128;
    }
    const size_t kbase = (size_t)blockIdx.z * Ks;
    const int tid = threadIdx.x;
    const int wave = tid >> 6, lane = tid & 63;
    const int wm = (wave >> 1) * (BM / 2), wn = (wave & 1) * (BN / 2);
    const int l15 = lane & 15, quad = lane >> 4;
    const int l7 = l15 & 7;   // == row&7 of this lane's fragment rows

    f32x4_t acc[MI][NI];
    #pragma unroll
    for (int mi = 0; mi < MI; ++mi)
        #pragma unroll
        for (int ni = 0; ni < NI; ++ni)
            acc[mi][ni] = (f32x4_t){0.f, 0.f, 0.f, 0.f};

    auto stage = [&](int k0) {
        #pragma unroll
        for (int c = 0; c < BM / 32; ++c) {       // A: BM*128 B
            const int o = c * 4096 + tid * 16;
            const int row = o >> 7;
            const int g = ((o >> 4) & 7) ^ (row & 7);
            gload16(A + (size_t)(bm + row) * Kst + kbase + k0 + g * 8,
                    (char*)As + c * 4096 + wave * 1024);
        }
        #pragma unroll
        for (int c = 0; c < BN / 32; ++c) {       // B: BN*128 B
            const int o = c * 4096 + tid * 16;
            const int row = o >> 7;
            const int g = ((o >> 4) & 7) ^ (row & 7);
            gload16(W + (size_t)(bn + row) * Kst + kbase + k0 + g * 8,
                    (char*)Bs + c * 4096 + wave * 1024);
        }
    };

    const int nIter = Ks >> 6;
    for (int it = 0; it < nIter; ++it) {
        __syncthreads();            // prev compute done reading LDS
        stage(it * 64);
        __syncthreads();            // drains vmcnt(0): staged data visible
        #pragma unroll
        for (int h = 0; h < 2; ++h) {
            const int fg = (((h << 2) | quad) ^ l7) * 8;
            short8_t af[MI], bf[NI];
            #pragma unroll
            for (int mi = 0; mi < MI; ++mi)
                af[mi] = *(const short8_t*)&As[(wm + mi * 16 + l15) * 64 + fg];
            #pragma unroll
            for (int ni = 0; ni < NI; ++ni)
                bf[ni] = *(const short8_t*)&Bs[(wn + ni * 16 + l15) * 64 + fg];
            #pragma unroll
            for (int mi = 0; mi < MI; ++mi)
                #pragma unroll
                for (int ni = 0; ni < NI; ++ni)
                    acc[mi][ni] = __builtin_amdgcn_mfma_f32_16x16x32_bf16(
                        af[mi], bf[ni], acc[mi][ni], 0, 0, 0);
        }
    }

    // ---- epilogue ----
    if (EPI == 4 || (EPI == 8 && (bn + wn) < 1024)) {
        // l2norm over each 64-col head group (NI/4 groups per wave)
        #pragma unroll
        for (int g = 0; g < NI / 4; ++g)
            #pragma unroll
            for (int mi = 0; mi < MI; ++mi)
                #pragma unroll
                for (int r = 0; r < 4; ++r) {
                    float s = 0.f;
                    #pragma unroll
                    for (int ni = g * 4; ni < g * 4 + 4; ++ni) {
                        const float x = acc[mi][ni][r];
                        s += x * x;
                    }
                    s += __shfl_xor(s, 1); s += __shfl_xor(s, 2);
                    s += __shfl_xor(s, 4); s += __shfl_xor(s, 8);
                    const float sc = 1.0f / fmaxf(sqrtf(s), 1e-6f);
                    #pragma unroll
                    for (int ni = g * 4; ni < g * 4 + 4; ++ni)
                        acc[mi][ni][r] *= sc;
                }
    }

    const float a = (EPI == 1) ? alpha[0] : 0.f;
    #pragma unroll
    for (int mi = 0; mi < MI; ++mi) {
        #pragma unroll
        for (int ni = 0; ni < NI; ++ni) {
            const int n = bn + wn + ni * 16 + l15;
            const float bb = (EPI == 1 || EPI == 2) ? bias[n] : 0.f;
            #pragma unroll
            for (int r = 0; r < 4; ++r) {
                const int m = bm + wm + mi * 16 + (quad << 2) + r;
                const float x = acc[mi][ni][r];
                if (EPI == 4) {
                    out16[(size_t)m * N + n] = f2b(x);
                } else if (EPI == 1) {
                    const size_t idx = (size_t)m * N + n;
                    outF[idx] = resF[idx] + a * (x + bb);
                } else if (EPI == 2) {
                    const float t = x + bb;
                    out16[(size_t)m * N + n] =
                        f2b(0.5f * t * (1.0f + erff(t * 0.70710678118f)));
                } else if (EPI == 7) {
                    outF[(size_t)blockIdx.z * M * N + (size_t)m * N + n] = x;
                } else if (EPI == 8) {
                    if (n < 1024) {       // khd[b,h,kv,d]
                        out16[(size_t)(((m >> 11) * 16 + (n >> 6)) * 2048 +
                                       (m & 2047)) * 64 + (n & 63)] = f2b(x);
                    } else {              // vhd[b,h,d,kv]
                        const int nn = n - 1024;
                        ((short*)outF)[(size_t)(((m >> 11) * 16 + (nn >> 6)) * 64 +
                                       (nn & 63)) * 2048 + (m & 2047)] = f2b(x);
                    }
                }
            }
        }
    }
}

// ---------------------------------------------------------------------------
// Split-K reduce for fc2: out = resF + alpha*(p0+p1+p2+p3 + bias). N=1024.
// ---------------------------------------------------------------------------
__global__ __launch_bounds__(256) void reduce4_kernel(
    const float* __restrict__ parts, const float* __restrict__ resF,
    const float* __restrict__ bias, const float* __restrict__ alpha,
    float* __restrict__ out)
{
    const int i = blockIdx.x * 256 + threadIdx.x;   // float4 index over 2048x1024
    const size_t MN4 = (size_t)2048 * 1024 / 4;
    const float a = alpha[0];
    const float4 b4 = ((const float4*)bias)[i & 255];
    float4 s = ((const float4*)parts)[i];
    const float4 p1 = ((const float4*)parts)[MN4 + i];
    const float4 p2 = ((const float4*)parts)[2 * MN4 + i];
    const float4 p3 = ((const float4*)parts)[3 * MN4 + i];
    const float4 rv = ((const float4*)resF)[i];
    float4 o;
    o.x = rv.x + a * (s.x + p1.x + p2.x + p3.x + b4.x);
    o.y = rv.y + a * (s.y + p1.y + p2.y + p3.y + b4.y);
    o.z = rv.z + a * (s.z + p1.z + p2.z + p3.z + b4.z);
    o.w = rv.w + a * (s.w + p1.w + p2.w + p3.w + b4.w);
    ((float4*)out)[i] = o;
}

// ---------------------------------------------------------------------------
// Attention: block = (q-tile 128, head, batch) = 256 blocks; 4 waves x 32 Q.
// K/V tiles (64x64) staged via global_load_lds, double-buffered, 1 barrier
// per tile, 128 B LDS rows + 3-bit row XOR (conflict-free b128 reads).
// No running max needed: |q.k| <= 1 after l2norm.
// ---------------------------------------------------------------------------
__global__ __launch_bounds__(256) void attn_kernel(
    const short* __restrict__ q, const short* __restrict__ khd,
    const short* __restrict__ vhd, short* __restrict__ ctx)
{
    const int qt = blockIdx.x;   // 0..3
    const int h  = blockIdx.y;   // 0..15
    const int b  = blockIdx.z;   // 0..3
    const int tid = threadIdx.x;
    const int wave = tid >> 6, lane = tid & 63;
    const int l15 = lane & 15, quad = lane >> 4;
    const int q0 = qt * 128 + wave * 32;

    __shared__ __attribute__((aligned(16))) short Ks[2][4096];
    __shared__ __attribute__((aligned(16))) short Vs[2][4096];
    __shared__ __attribute__((aligned(16))) short P[4][2304];   // 32 x 72

    short8_t aq[2][2];
    #pragma unroll
    for (int qi = 0; qi < 2; ++qi) {
        const short* qb =
            q + (size_t)(b * 512 + q0 + qi * 16 + l15) * 1024 + h * 64 + quad * 8;
        aq[qi][0] = *(const short8_t*)(qb);
        aq[qi][1] = *(const short8_t*)(qb + 32);
    }

    const short* kbase = khd + (size_t)(b * 16 + h) * 2048 * 64;  // [2048][64]
    const short* vbase = vhd + (size_t)(b * 16 + h) * 64 * 2048;  // [64][2048]

    const int swz = l15 & 7;
    const int g0 = (quad ^ swz) * 8;
    const int g1 = ((quad ^ swz) ^ 4) * 8;

    auto stage = [&](int buf, int t) {
        #pragma unroll
        for (int c = 0; c < 2; ++c) {
            const int o = c * 4096 + tid * 16;
            const int row = o >> 7;              // 64 rows x 128 B
            const int g = ((o >> 4) & 7) ^ (row & 7);
            gload16(kbase + (size_t)(t * 64 + row) * 64 + g * 8,
                    (char*)Ks[buf] + c * 4096 + wave * 1024);
            gload16(vbase + (size_t)row * 2048 + t * 64 + g * 8,
                    (char*)Vs[buf] + c * 4096 + wave * 1024);
        }
    };

    f32x4_t oacc[2][4];
    float l[2][4];
    #pragma unroll
    for (int qi = 0; qi < 2; ++qi)
        #pragma unroll
        for (int u = 0; u < 4; ++u) {
            oacc[qi][u] = (f32x4_t){0.f, 0.f, 0.f, 0.f};
            l[qi][u] = 0.f;
        }

    stage(0, 0);
    for (int t = 0; t < 32; ++t) {
        const int buf = t & 1;
        __syncthreads();
        if (t + 1 < 32) stage(buf ^ 1, t + 1);

        // S = Q K^T  (32 q x 64 kv per wave)
        f32x4_t s[2][4];
        #pragma unroll
        for (int ss = 0; ss < 4; ++ss) {
            const int R = ss * 16 + l15;
            const short8_t bk0 = *(const short8_t*)&Ks[buf][R * 64 + g0];
            const short8_t bk1 = *(const short8_t*)&Ks[buf][R * 64 + g1];
            #pragma unroll
            for (int qi = 0; qi < 2; ++qi) {
                f32x4_t a = (f32x4_t){0.f, 0.f, 0.f, 0.f};
                a = __builtin_amdgcn_mfma_f32_16x16x32_bf16(aq[qi][0], bk0, a, 0, 0, 0);
                a = __builtin_amdgcn_mfma_f32_16x16x32_bf16(aq[qi][1], bk1, a, 0, 0, 0);
                s[qi][ss] = a;
            }
        }
        // P = exp(S/2), row sums
        #pragma unroll
        for (int qi = 0; qi < 2; ++qi) {
            float rs[4] = {0.f, 0.f, 0.f, 0.f};
            #pragma unroll
            for (int ss = 0; ss < 4; ++ss)
                #pragma unroll
                for (int r = 0; r < 4; ++r) {
                    const float p = __expf(s[qi][ss][r] * 0.5f);
                    s[qi][ss][r] = p;
                    rs[r] += p;
                }
            #pragma unroll
            for (int r = 0; r < 4; ++r) {
                float v = rs[r];
                v += __shfl_xor(v, 1); v += __shfl_xor(v, 2);
                v += __shfl_xor(v, 4); v += __shfl_xor(v, 8);
                l[qi][r] += v;
            }
        }
        // P: C-layout -> LDS (wave-private region) -> A-layout fragments
        #pragma unroll
        for (int qi = 0; qi < 2; ++qi)
            #pragma unroll
            for (int ss = 0; ss < 4; ++ss)
                #pragma unroll
                for (int r = 0; r < 4; ++r)
                    P[wave][(qi * 16 + quad * 4 + r) * 72 + ss * 16 + l15] =
                        f2b(s[qi][ss][r]);
        short8_t ap[2][2];
        #pragma unroll
        for (int qi = 0; qi < 2; ++qi) {
            ap[qi][0] = *(const short8_t*)&P[wave][(qi * 16 + l15) * 72 + quad * 8];
            ap[qi][1] = *(const short8_t*)&P[wave][(qi * 16 + l15) * 72 + 32 + quad * 8];
        }
        // O += P V   (32 q x 64 d per wave)
        #pragma unroll
        for (int u = 0; u < 4; ++u) {
            const int R = u * 16 + l15;
            const short8_t bv0 = *(const short8_t*)&Vs[buf][R * 64 + g0];
            const short8_t bv1 = *(const short8_t*)&Vs[buf][R * 64 + g1];
            #pragma unroll
            for (int qi = 0; qi < 2; ++qi) {
                oacc[qi][u] = __builtin_amdgcn_mfma_f32_16x16x32_bf16(
                    ap[qi][0], bv0, oacc[qi][u], 0, 0, 0);
                oacc[qi][u] = __builtin_amdgcn_mfma_f32_16x16x32_bf16(
                    ap[qi][1], bv1, oacc[qi][u], 0, 0, 0);
            }
        }
    }
    #pragma unroll
    for (int qi = 0; qi < 2; ++qi)
        #pragma unroll
        for (int u = 0; u < 4; ++u)
            #pragma unroll
            for (int r = 0; r < 4; ++r) {
                const float val = oacc[qi][u][r] / l[qi][r];
                ctx[(size_t)(b * 512 + q0 + qi * 16 + quad * 4 + r) * 1024 +
                    h * 64 + u * 16 + l15] = f2b(val);
            }
}

// ---------------------------------------------------------------------------
extern "C" void kernel_launch(void* const* d_in, const int* in_sizes, int n_in,
                              void* d_out, int out_size, void* d_ws, size_t ws_size,
                              hipStream_t stream)
{
    const float* q_tokens  = (const float*)d_in[0];
    const float* kv_tokens = (const float*)d_in[1];
    const float* q_ln_w    = (const float*)d_in[2];
    const float* q_ln_b    = (const float*)d_in[3];
    const float* kv_ln_w   = (const float*)d_in[4];
    const float* kv_ln_b   = (const float*)d_in[5];
    const float* mlp_ln_w  = (const float*)d_in[6];
    const float* mlp_ln_b  = (const float*)d_in[7];
    const float* Wq        = (const float*)d_in[8];
    const float* Wk        = (const float*)d_in[9];
    const float* Wv        = (const float*)d_in[10];
    const float* Wo        = (const float*)d_in[11];
    const float* bo        = (const float*)d_in[12];
    const float* fc1_w     = (const float*)d_in[13];
    const float* fc1_b     = (const float*)d_in[14];
    const float* fc2_w     = (const float*)d_in[15];
    const float* fc2_b     = (const float*)d_in[16];
    const float* alpha_attn = (const float*)d_in[17];
    const float* alpha_mlp  = (const float*)d_in[18];

    char* ws = (char*)d_ws;
    const size_t MB = (size_t)1 << 20;
    short* khd   = (short*)(ws);             // 16 MB [4,16,2048,64]; dead after attn
    short* vhd   = (short*)(ws + 16 * MB);   // 16 MB [4,16,64,2048]; dead after attn
    float* parts = (float*)(ws);             // 32 MB fc2 split-K partials (overlays khd+vhd)
    short* kvn   = (short*)(ws + 32 * MB);   // 16 MB [8192,1024]; dead after kv-proj
    short* h1    = (short*)(ws + 32 * MB);   //       overlays kvn: [2048,4096]
    short* qn    = (short*)(ws + 48 * MB);   //  4 MB [2048,1024]
    short* qbuf  = (short*)(ws + 52 * MB);   //  4 MB [2048,1024] (l2-normed q)
    short* ctx   = (short*)(ws + 56 * MB);   //  4 MB [2048,1024]
    float* aout  = (float*)(ws + 60 * MB);   //  8 MB [2048,1024] fp32
    short* hn    = (short*)(ws + 68 * MB);   //  4 MB [2048,1024]
    short* Wq_b  = (short*)(ws + 72 * MB);   //  2 MB
    short* Wkv_b = (short*)(ws + 74 * MB);   //  4 MB stacked [2048,1024]
    short* Wo_b  = (short*)(ws + 78 * MB);   //  2 MB
    short* fc1_wb = (short*)(ws + 80 * MB);  //  8 MB
    short* fc2_wb = (short*)(ws + 88 * MB);  //  8 MB

    // 0) fused: q-LN + kv-LN + weight casts (Wk/Wv stacked)
    prep_kernel<<<22528, 256, 0, stream>>>(
        q_tokens, kv_tokens, q_ln_w, q_ln_b, kv_ln_w, kv_ln_b, qn, kvn,
        Wq, Wk, Wv, Wo, fc1_w, fc2_w,
        Wq_b, Wkv_b, Wkv_b + 1048576, Wo_b, fc1_wb, fc2_wb);

    // 1) q-proj (+l2norm) and fused kv-proj (+l2norm/scatter, 128x256, XCD swz)
    gemm_bt_kernel<4, 64, 128, 0><<<dim3(8, 32), 256, 0, stream>>>(
        qn, Wq_b, 2048, 1024, 1024, 1024, nullptr, nullptr, nullptr, qbuf, nullptr);
    gemm_bt_kernel<8, 128, 256, 1><<<512, 256, 0, stream>>>(
        kvn, Wkv_b, 8192, 2048, 1024, 1024, nullptr, nullptr, nullptr,
        khd, (float*)vhd);

    // 2) Attention (q-tile 128)
    attn_kernel<<<dim3(4, 16, 4), 256, 0, stream>>>(qbuf, khd, vhd, ctx);

    // 3) Out-proj + residual: aout = q_tokens + alpha*(ctx@Wo^T + bo)
    gemm_bt_kernel<1, 64, 128, 0><<<dim3(8, 32), 256, 0, stream>>>(
        ctx, Wo_b, 2048, 1024, 1024, 1024, bo, q_tokens, alpha_attn, nullptr, aout);

    // 4) MLP LN
    ln_kernel<<<2048, 256, 0, stream>>>(aout, mlp_ln_w, mlp_ln_b, hn);

    // 5) fc1 + exact GELU (XCD swz)
    gemm_bt_kernel<2, 128, 128, 2><<<512, 256, 0, stream>>>(
        hn, fc1_wb, 2048, 4096, 1024, 1024, fc1_b, nullptr, nullptr, h1, nullptr);

    // 6) fc2 split-K x4 -> fp32 partials, then reduce + residual -> d_out
    gemm_bt_kernel<7, 64, 128, 0><<<dim3(8, 32, 4), 256, 0, stream>>>(
        h1, fc2_wb, 2048, 1024, 1024, 4096, nullptr, nullptr, nullptr,
        nullptr, parts);
    reduce4_kernel<<<2048, 256, 0, stream>>>(parts, aout, fc2_b, alpha_mlp,
                                             (float*)d_out);
}

// Round 7
// 397.935 us; speedup vs baseline: 1.0603x; 1.0603x over previous
//
#include <hip/hip_runtime.h>

// ---------------------------------------------------------------------------
// CrossAttentionBlockPatched: B=4, Lq=512, Lkv=2048, DIM=1024, H=16, hd=64,
// MLP_HIDDEN=4096, TAU=2.0, EPS=1e-6. fp32 in/out, bf16 MFMA internally.
// ---------------------------------------------------------------------------

typedef __attribute__((ext_vector_type(8))) short short8_t;   // 8 x bf16
typedef __attribute__((ext_vector_type(4))) float f32x4_t;    // 4 x fp32

__device__ __forceinline__ float b2f(short s) {
    union { float f; unsigned u; } c;
    c.u = ((unsigned)(unsigned short)s) << 16;
    return c.f;
}
__device__ __forceinline__ short f2b(float f) {
    union { float f; unsigned u; } c;
    c.f = f;
    unsigned u = c.u;
    unsigned r = (u + 0x7FFFu + ((u >> 16) & 1u)) >> 16;
    return (short)r;
}

// async global -> LDS, 16 B per lane; lds base must be wave-uniform.
__device__ __forceinline__ void gload16(const void* g, void* l) {
    __builtin_amdgcn_global_load_lds(
        (const __attribute__((address_space(1))) void*)g,
        (__attribute__((address_space(3))) void*)l, 16, 0, 0);
}

// ---------------------------------------------------------------------------
// prep: fused q-LN (blocks 0..2047), kv-LN (2048..10239), weight cast
// (10240..22527). LN: fp32 in, bf16 out, one block per 1024-elem row.
// ---------------------------------------------------------------------------
__device__ __forceinline__ void ln_row(
    const float* __restrict__ x, const float* __restrict__ w,
    const float* __restrict__ bia, short* __restrict__ y,
    int row, int tid, float* red)
{
    const float4 t = *(const float4*)(x + (size_t)row * 1024 + tid * 4);
    float v[4] = {t.x, t.y, t.z, t.w};
    float s = v[0] + v[1] + v[2] + v[3];
    float s2 = v[0]*v[0] + v[1]*v[1] + v[2]*v[2] + v[3]*v[3];
    #pragma unroll
    for (int off = 1; off < 64; off <<= 1) {
        s  += __shfl_xor(s, off);
        s2 += __shfl_xor(s2, off);
    }
    const int wave = tid >> 6, lane = tid & 63;
    if (lane == 0) { red[wave] = s; red[4 + wave] = s2; }
    __syncthreads();
    s  = red[0] + red[1] + red[2] + red[3];
    s2 = red[4] + red[5] + red[6] + red[7];
    const float mu  = s * (1.0f / 1024.0f);
    const float var = s2 * (1.0f / 1024.0f) - mu * mu;
    const float rstd = rsqrtf(var + 1e-6f);
    const float4 wv = *(const float4*)(w + tid * 4);
    const float4 bv = *(const float4*)(bia + tid * 4);
    short4 o;
    o.x = f2b((v[0] - mu) * rstd * wv.x + bv.x);
    o.y = f2b((v[1] - mu) * rstd * wv.y + bv.y);
    o.z = f2b((v[2] - mu) * rstd * wv.z + bv.z);
    o.w = f2b((v[3] - mu) * rstd * wv.w + bv.w);
    *(short4*)(y + (size_t)row * 1024 + tid * 4) = o;
}

__global__ __launch_bounds__(256) void prep_kernel(
    const float* __restrict__ qt, const float* __restrict__ kvt,
    const float* __restrict__ qlw, const float* __restrict__ qlb,
    const float* __restrict__ klw, const float* __restrict__ klb,
    short* __restrict__ qn, short* __restrict__ kvn,
    const float* __restrict__ w0, const float* __restrict__ w1,
    const float* __restrict__ w2, const float* __restrict__ w3,
    const float* __restrict__ w4, const float* __restrict__ w5,
    short* __restrict__ o0, short* __restrict__ o1,
    short* __restrict__ o2, short* __restrict__ o3,
    short* __restrict__ o4, short* __restrict__ o5)
{
    __shared__ float red[8];
    const int bid = blockIdx.x, tid = threadIdx.x;
    if (bid < 2048) {
        ln_row(qt, qlw, qlb, qn, bid, tid, red);
    } else if (bid < 10240) {
        ln_row(kvt, klw, klb, kvn, bid - 2048, tid, red);
    } else {
        int f = (bid - 10240) * 256 + tid;   // float4 index, total 3145728
        const float* src; short* dst; int off;
        if (f < 1048576) {
            const int which = f >> 18; off = f & 262143;
            src = which == 0 ? w0 : which == 1 ? w1 : which == 2 ? w2 : w3;
            dst = which == 0 ? o0 : which == 1 ? o1 : which == 2 ? o2 : o3;
        } else {
            f -= 1048576;
            const int which = f >> 20; off = f & 1048575;
            src = which ? w5 : w4; dst = which ? o5 : o4;
        }
        const float4 v = ((const float4*)src)[off];
        short4 o;
        o.x = f2b(v.x); o.y = f2b(v.y); o.z = f2b(v.z); o.w = f2b(v.w);
        ((short4*)dst)[off] = o;
    }
}

// ---------------------------------------------------------------------------
// LayerNorm (standalone, for MLP LN): fp32 in, bf16 out.
// ---------------------------------------------------------------------------
__global__ __launch_bounds__(256) void ln_kernel(
    const float* __restrict__ x, const float* __restrict__ w,
    const float* __restrict__ bia, short* __restrict__ y)
{
    __shared__ float red[8];
    ln_row(x, w, bia, y, blockIdx.x, threadIdx.x, red);
}

// ---------------------------------------------------------------------------
// GEMM: C[M,N] = epilogue(A[M,K] @ W[N,K]^T), bf16 in, BN=128, BK=64.
// Double-buffered LDS, ONE barrier per K-step: stage(t+1) is issued right
// after the barrier and stays in flight during compute(t) (the barrier's
// vmcnt(0) drain at iter t+1 completes it). 128 B LDS rows, 3-bit XOR
// swizzle -> conflict-free ds_read_b128.
// BM=128: 4 waves as 2x2, wave 64x64 (MI=4, VGPR ~90 -> 2 blocks/CU w/ 64KB).
// BM=64:  wave 32x64 (MI=2).
// EPI: 1 outF = resF + alpha*(acc+bias) (fp32)
//      2 gelu_exact(acc+bias) bf16 (fc1)
//      4 l2norm(row, 64-col head) bf16 (q-proj)
//      7 fp32 partial to outF + z*M*N (split-K)
//      8 fused KV: n<1024 -> l2norm + scatter khd[b,h,kv,d] (out16);
//                  n>=1024 -> scatter vhd[b,h,d,kv] ((short*)outF)
// ---------------------------------------------------------------------------
template <int EPI, int BM>
__global__ __launch_bounds__(256) void gemm_bt_kernel(
    const short* __restrict__ A, const short* __restrict__ W,
    int M, int N, int Ks, int Kst,
    const float* __restrict__ bias,
    const float* __restrict__ resF,
    const float* __restrict__ alpha,
    short* __restrict__ out16,
    float* __restrict__ outF)
{
    constexpr int MI = BM / 32;
    __shared__ __attribute__((aligned(16))) short As[2][BM * 64];
    __shared__ __attribute__((aligned(16))) short Bs[2][128 * 64];
    const int bm = blockIdx.y * BM, bn = blockIdx.x * 128;
    const size_t kbase = (size_t)blockIdx.z * Ks;
    const int tid = threadIdx.x;
    const int wave = tid >> 6, lane = tid & 63;
    const int wm = (wave >> 1) * (BM / 2), wn = (wave & 1) * 64;
    const int l15 = lane & 15, quad = lane >> 4;
    const int l7 = l15 & 7;   // == row&7 of this lane's fragment rows

    f32x4_t acc[MI][4];
    #pragma unroll
    for (int mi = 0; mi < MI; ++mi)
        #pragma unroll
        for (int ni = 0; ni < 4; ++ni)
            acc[mi][ni] = (f32x4_t){0.f, 0.f, 0.f, 0.f};

    auto stage = [&](int buf, int k0) {
        #pragma unroll
        for (int c = 0; c < BM / 32; ++c) {       // A: BM*128 B
            const int o = c * 4096 + tid * 16;
            const int row = o >> 7;
            const int g = ((o >> 4) & 7) ^ (row & 7);
            gload16(A + (size_t)(bm + row) * Kst + kbase + k0 + g * 8,
                    (char*)As[buf] + c * 4096 + wave * 1024);
        }
        #pragma unroll
        for (int c = 0; c < 4; ++c) {             // B: 128*128 B
            const int o = c * 4096 + tid * 16;
            const int row = o >> 7;
            const int g = ((o >> 4) & 7) ^ (row & 7);
            gload16(W + (size_t)(bn + row) * Kst + kbase + k0 + g * 8,
                    (char*)Bs[buf] + c * 4096 + wave * 1024);
        }
    };

    const int nIter = Ks >> 6;
    stage(0, 0);
    for (int it = 0; it < nIter; ++it) {
        const int buf = it & 1;
        __syncthreads();   // drains stage(it) vmem; prev compute done w/ buf^1
        if (it + 1 < nIter) stage(buf ^ 1, (it + 1) * 64);
        #pragma unroll
        for (int h = 0; h < 2; ++h) {
            const int fg = (((h << 2) | quad) ^ l7) * 8;
            short8_t af[MI], bf[4];
            #pragma unroll
            for (int mi = 0; mi < MI; ++mi)
                af[mi] = *(const short8_t*)&As[buf][(wm + mi * 16 + l15) * 64 + fg];
            #pragma unroll
            for (int ni = 0; ni < 4; ++ni)
                bf[ni] = *(const short8_t*)&Bs[buf][(wn + ni * 16 + l15) * 64 + fg];
            #pragma unroll
            for (int mi = 0; mi < MI; ++mi)
                #pragma unroll
                for (int ni = 0; ni < 4; ++ni)
                    acc[mi][ni] = __builtin_amdgcn_mfma_f32_16x16x32_bf16(
                        af[mi], bf[ni], acc[mi][ni], 0, 0, 0);
        }
    }

    // ---- epilogue ----
    if (EPI == 4 || (EPI == 8 && (bn + wn) < 1024)) {   // l2norm over 64-col head
        #pragma unroll
        for (int mi = 0; mi < MI; ++mi)
            #pragma unroll
            for (int r = 0; r < 4; ++r) {
                float s = 0.f;
                #pragma unroll
                for (int ni = 0; ni < 4; ++ni) {
                    const float x = acc[mi][ni][r];
                    s += x * x;
                }
                s += __shfl_xor(s, 1); s += __shfl_xor(s, 2);
                s += __shfl_xor(s, 4); s += __shfl_xor(s, 8);
                const float sc = 1.0f / fmaxf(sqrtf(s), 1e-6f);
                #pragma unroll
                for (int ni = 0; ni < 4; ++ni) acc[mi][ni][r] *= sc;
            }
    }

    const float a = (EPI == 1) ? alpha[0] : 0.f;
    #pragma unroll
    for (int mi = 0; mi < MI; ++mi) {
        #pragma unroll
        for (int ni = 0; ni < 4; ++ni) {
            const int n = bn + wn + ni * 16 + l15;
            const float bb = (EPI == 1 || EPI == 2) ? bias[n] : 0.f;
            #pragma unroll
            for (int r = 0; r < 4; ++r) {
                const int m = bm + wm + mi * 16 + (quad << 2) + r;
                const float x = acc[mi][ni][r];
                if (EPI == 4) {
                    out16[(size_t)m * N + n] = f2b(x);
                } else if (EPI == 1) {
                    const size_t idx = (size_t)m * N + n;
                    outF[idx] = resF[idx] + a * (x + bb);
                } else if (EPI == 2) {
                    const float t = x + bb;
                    out16[(size_t)m * N + n] =
                        f2b(0.5f * t * (1.0f + erff(t * 0.70710678118f)));
                } else if (EPI == 7) {
                    outF[(size_t)blockIdx.z * M * N + (size_t)m * N + n] = x;
                } else if (EPI == 8) {
                    if (n < 1024) {       // khd[b,h,kv,d]
                        out16[(size_t)(((m >> 11) * 16 + (n >> 6)) * 2048 +
                                       (m & 2047)) * 64 + (n & 63)] = f2b(x);
                    } else {              // vhd[b,h,d,kv]
                        const int nn = n - 1024;
                        ((short*)outF)[(size_t)(((m >> 11) * 16 + (nn >> 6)) * 64 +
                                       (nn & 63)) * 2048 + (m & 2047)] = f2b(x);
                    }
                }
            }
        }
    }
}

// ---------------------------------------------------------------------------
// Split-K reduce for fc2: out = resF + alpha*(p0+p1+p2+p3 + bias). N=1024.
// ---------------------------------------------------------------------------
__global__ __launch_bounds__(256) void reduce4_kernel(
    const float* __restrict__ parts, const float* __restrict__ resF,
    const float* __restrict__ bias, const float* __restrict__ alpha,
    float* __restrict__ out)
{
    const int i = blockIdx.x * 256 + threadIdx.x;   // float4 index over 2048x1024
    const size_t MN4 = (size_t)2048 * 1024 / 4;
    const float a = alpha[0];
    const float4 b4 = ((const float4*)bias)[i & 255];
    float4 s = ((const float4*)parts)[i];
    const float4 p1 = ((const float4*)parts)[MN4 + i];
    const float4 p2 = ((const float4*)parts)[2 * MN4 + i];
    const float4 p3 = ((const float4*)parts)[3 * MN4 + i];
    const float4 rv = ((const float4*)resF)[i];
    float4 o;
    o.x = rv.x + a * (s.x + p1.x + p2.x + p3.x + b4.x);
    o.y = rv.y + a * (s.y + p1.y + p2.y + p3.y + b4.y);
    o.z = rv.z + a * (s.z + p1.z + p2.z + p3.z + b4.z);
    o.w = rv.w + a * (s.w + p1.w + p2.w + p3.w + b4.w);
    ((float4*)out)[i] = o;
}

// ---------------------------------------------------------------------------
// Attention: block = (q-tile 128, head, batch) = 256 blocks; 4 waves x 32 Q.
// K/V tiles (64x64) staged via global_load_lds, double-buffered, 1 barrier
// per tile, 128 B LDS rows + 3-bit row XOR (conflict-free b128 reads).
// No running max needed: |q.k| <= 1 after l2norm.
// ---------------------------------------------------------------------------
__global__ __launch_bounds__(256) void attn_kernel(
    const short* __restrict__ q, const short* __restrict__ khd,
    const short* __restrict__ vhd, short* __restrict__ ctx)
{
    const int qt = blockIdx.x;   // 0..3
    const int h  = blockIdx.y;   // 0..15
    const int b  = blockIdx.z;   // 0..3
    const int tid = threadIdx.x;
    const int wave = tid >> 6, lane = tid & 63;
    const int l15 = lane & 15, quad = lane >> 4;
    const int q0 = qt * 128 + wave * 32;

    __shared__ __attribute__((aligned(16))) short Ks[2][4096];
    __shared__ __attribute__((aligned(16))) short Vs[2][4096];
    __shared__ __attribute__((aligned(16))) short P[4][2304];   // 32 x 72

    short8_t aq[2][2];
    #pragma unroll
    for (int qi = 0; qi < 2; ++qi) {
        const short* qb =
            q + (size_t)(b * 512 + q0 + qi * 16 + l15) * 1024 + h * 64 + quad * 8;
        aq[qi][0] = *(const short8_t*)(qb);
        aq[qi][1] = *(const short8_t*)(qb + 32);
    }

    const short* kbase = khd + (size_t)(b * 16 + h) * 2048 * 64;  // [2048][64]
    const short* vbase = vhd + (size_t)(b * 16 + h) * 64 * 2048;  // [64][2048]

    const int swz = l15 & 7;
    const int g0 = (quad ^ swz) * 8;
    const int g1 = ((quad ^ swz) ^ 4) * 8;

    auto stage = [&](int buf, int t) {
        #pragma unroll
        for (int c = 0; c < 2; ++c) {
            const int o = c * 4096 + tid * 16;
            const int row = o >> 7;              // 64 rows x 128 B
            const int g = ((o >> 4) & 7) ^ (row & 7);
            gload16(kbase + (size_t)(t * 64 + row) * 64 + g * 8,
                    (char*)Ks[buf] + c * 4096 + wave * 1024);
            gload16(vbase + (size_t)row * 2048 + t * 64 + g * 8,
                    (char*)Vs[buf] + c * 4096 + wave * 1024);
        }
    };

    f32x4_t oacc[2][4];
    float l[2][4];
    #pragma unroll
    for (int qi = 0; qi < 2; ++qi)
        #pragma unroll
        for (int u = 0; u < 4; ++u) {
            oacc[qi][u] = (f32x4_t){0.f, 0.f, 0.f, 0.f};
            l[qi][u] = 0.f;
        }

    stage(0, 0);
    for (int t = 0; t < 32; ++t) {
        const int buf = t & 1;
        __syncthreads();
        if (t + 1 < 32) stage(buf ^ 1, t + 1);

        // S = Q K^T  (32 q x 64 kv per wave)
        f32x4_t s[2][4];
        #pragma unroll
        for (int ss = 0; ss < 4; ++ss) {
            const int R = ss * 16 + l15;
            const short8_t bk0 = *(const short8_t*)&Ks[buf][R * 64 + g0];
            const short8_t bk1 = *(const short8_t*)&Ks[buf][R * 64 + g1];
            #pragma unroll
            for (int qi = 0; qi < 2; ++qi) {
                f32x4_t a = (f32x4_t){0.f, 0.f, 0.f, 0.f};
                a = __builtin_amdgcn_mfma_f32_16x16x32_bf16(aq[qi][0], bk0, a, 0, 0, 0);
                a = __builtin_amdgcn_mfma_f32_16x16x32_bf16(aq[qi][1], bk1, a, 0, 0, 0);
                s[qi][ss] = a;
            }
        }
        // P = exp(S/2), row sums
        #pragma unroll
        for (int qi = 0; qi < 2; ++qi) {
            float rs[4] = {0.f, 0.f, 0.f, 0.f};
            #pragma unroll
            for (int ss = 0; ss < 4; ++ss)
                #pragma unroll
                for (int r = 0; r < 4; ++r) {
                    const float p = __expf(s[qi][ss][r] * 0.5f);
                    s[qi][ss][r] = p;
                    rs[r] += p;
                }
            #pragma unroll
            for (int r = 0; r < 4; ++r) {
                float v = rs[r];
                v += __shfl_xor(v, 1); v += __shfl_xor(v, 2);
                v += __shfl_xor(v, 4); v += __shfl_xor(v, 8);
                l[qi][r] += v;
            }
        }
        // P: C-layout -> LDS (wave-private region) -> A-layout fragments
        #pragma unroll
        for (int qi = 0; qi < 2; ++qi)
            #pragma unroll
            for (int ss = 0; ss < 4; ++ss)
                #pragma unroll
                for (int r = 0; r < 4; ++r)
                    P[wave][(qi * 16 + quad * 4 + r) * 72 + ss * 16 + l15] =
                        f2b(s[qi][ss][r]);
        short8_t ap[2][2];
        #pragma unroll
        for (int qi = 0; qi < 2; ++qi) {
            ap[qi][0] = *(const short8_t*)&P[wave][(qi * 16 + l15) * 72 + quad * 8];
            ap[qi][1] = *(const short8_t*)&P[wave][(qi * 16 + l15) * 72 + 32 + quad * 8];
        }
        // O += P V   (32 q x 64 d per wave)
        #pragma unroll
        for (int u = 0; u < 4; ++u) {
            const int R = u * 16 + l15;
            const short8_t bv0 = *(const short8_t*)&Vs[buf][R * 64 + g0];
            const short8_t bv1 = *(const short8_t*)&Vs[buf][R * 64 + g1];
            #pragma unroll
            for (int qi = 0; qi < 2; ++qi) {
                oacc[qi][u] = __builtin_amdgcn_mfma_f32_16x16x32_bf16(
                    ap[qi][0], bv0, oacc[qi][u], 0, 0, 0);
                oacc[qi][u] = __builtin_amdgcn_mfma_f32_16x16x32_bf16(
                    ap[qi][1], bv1, oacc[qi][u], 0, 0, 0);
            }
        }
    }
    #pragma unroll
    for (int qi = 0; qi < 2; ++qi)
        #pragma unroll
        for (int u = 0; u < 4; ++u)
            #pragma unroll
            for (int r = 0; r < 4; ++r) {
                const float val = oacc[qi][u][r] / l[qi][r];
                ctx[(size_t)(b * 512 + q0 + qi * 16 + quad * 4 + r) * 1024 +
                    h * 64 + u * 16 + l15] = f2b(val);
            }
}

// ---------------------------------------------------------------------------
extern "C" void kernel_launch(void* const* d_in, const int* in_sizes, int n_in,
                              void* d_out, int out_size, void* d_ws, size_t ws_size,
                              hipStream_t stream)
{
    const float* q_tokens  = (const float*)d_in[0];
    const float* kv_tokens = (const float*)d_in[1];
    const float* q_ln_w    = (const float*)d_in[2];
    const float* q_ln_b    = (const float*)d_in[3];
    const float* kv_ln_w   = (const float*)d_in[4];
    const float* kv_ln_b   = (const float*)d_in[5];
    const float* mlp_ln_w  = (const float*)d_in[6];
    const float* mlp_ln_b  = (const float*)d_in[7];
    const float* Wq        = (const float*)d_in[8];
    const float* Wk        = (const float*)d_in[9];
    const float* Wv        = (const float*)d_in[10];
    const float* Wo        = (const float*)d_in[11];
    const float* bo        = (const float*)d_in[12];
    const float* fc1_w     = (const float*)d_in[13];
    const float* fc1_b     = (const float*)d_in[14];
    const float* fc2_w     = (const float*)d_in[15];
    const float* fc2_b     = (const float*)d_in[16];
    const float* alpha_attn = (const float*)d_in[17];
    const float* alpha_mlp  = (const float*)d_in[18];

    char* ws = (char*)d_ws;
    const size_t MB = (size_t)1 << 20;
    short* khd   = (short*)(ws);             // 16 MB [4,16,2048,64]; dead after attn
    short* vhd   = (short*)(ws + 16 * MB);   // 16 MB [4,16,64,2048]; dead after attn
    float* parts = (float*)(ws);             // 32 MB fc2 split-K partials (overlays khd+vhd)
    short* kvn   = (short*)(ws + 32 * MB);   // 16 MB [8192,1024]; dead after kv-proj
    short* h1    = (short*)(ws + 32 * MB);   //       overlays kvn: [2048,4096]
    short* qn    = (short*)(ws + 48 * MB);   //  4 MB [2048,1024]
    short* qbuf  = (short*)(ws + 52 * MB);   //  4 MB [2048,1024] (l2-normed q)
    short* ctx   = (short*)(ws + 56 * MB);   //  4 MB [2048,1024]
    float* aout  = (float*)(ws + 60 * MB);   //  8 MB [2048,1024] fp32
    short* hn    = (short*)(ws + 68 * MB);   //  4 MB [2048,1024]
    short* Wq_b  = (short*)(ws + 72 * MB);   //  2 MB
    short* Wkv_b = (short*)(ws + 74 * MB);   //  4 MB stacked [2048,1024]
    short* Wo_b  = (short*)(ws + 78 * MB);   //  2 MB
    short* fc1_wb = (short*)(ws + 80 * MB);  //  8 MB
    short* fc2_wb = (short*)(ws + 88 * MB);  //  8 MB

    // 0) fused: q-LN + kv-LN + weight casts (Wk/Wv stacked)
    prep_kernel<<<22528, 256, 0, stream>>>(
        q_tokens, kv_tokens, q_ln_w, q_ln_b, kv_ln_w, kv_ln_b, qn, kvn,
        Wq, Wk, Wv, Wo, fc1_w, fc2_w,
        Wq_b, Wkv_b, Wkv_b + 1048576, Wo_b, fc1_wb, fc2_wb);

    // 1) q-proj (+l2norm) and fused kv-proj (+l2norm/scatter)
    gemm_bt_kernel<4, 64><<<dim3(8, 32), 256, 0, stream>>>(
        qn, Wq_b, 2048, 1024, 1024, 1024, nullptr, nullptr, nullptr, qbuf, nullptr);
    gemm_bt_kernel<8, 128><<<dim3(16, 64), 256, 0, stream>>>(
        kvn, Wkv_b, 8192, 2048, 1024, 1024, nullptr, nullptr, nullptr,
        khd, (float*)vhd);

    // 2) Attention (q-tile 128)
    attn_kernel<<<dim3(4, 16, 4), 256, 0, stream>>>(qbuf, khd, vhd, ctx);

    // 3) Out-proj + residual: aout = q_tokens + alpha*(ctx@Wo^T + bo)
    gemm_bt_kernel<1, 64><<<dim3(8, 32), 256, 0, stream>>>(
        ctx, Wo_b, 2048, 1024, 1024, 1024, bo, q_tokens, alpha_attn, nullptr, aout);

    // 4) MLP LN
    ln_kernel<<<2048, 256, 0, stream>>>(aout, mlp_ln_w, mlp_ln_b, hn);

    // 5) fc1 + exact GELU
    gemm_bt_kernel<2, 128><<<dim3(32, 16), 256, 0, stream>>>(
        hn, fc1_wb, 2048, 4096, 1024, 1024, fc1_b, nullptr, nullptr, h1, nullptr);

    // 6) fc2 split-K x4 -> fp32 partials, then reduce + residual -> d_out
    gemm_bt_kernel<7, 64><<<dim3(8, 32, 4), 256, 0, stream>>>(
        h1, fc2_wb, 2048, 1024, 1024, 4096, nullptr, nullptr, nullptr,
        nullptr, parts);
    reduce4_kernel<<<2048, 256, 0, stream>>>(parts, aout, fc2_b, alpha_mlp,
                                             (float*)d_out);
}

// Round 8
// 359.706 us; speedup vs baseline: 1.1730x; 1.1063x over previous
//
#include <hip/hip_runtime.h>

// ---------------------------------------------------------------------------
// CrossAttentionBlockPatched: B=4, Lq=512, Lkv=2048, DIM=1024, H=16, hd=64,
// MLP_HIDDEN=4096, TAU=2.0, EPS=1e-6. fp32 in/out.
// Big GEMMs (kv-proj, fc1, fc2): fp8 e4m3 MFMA (weights pre-scaled x16).
// Small GEMMs (q-proj, Wo) + attention: bf16 MFMA. fp32 accumulation.
// ---------------------------------------------------------------------------

typedef __attribute__((ext_vector_type(8))) short short8_t;   // 8 x bf16
typedef __attribute__((ext_vector_type(4))) float f32x4_t;    // 4 x fp32

#define WSCALE 16.0f
#define OSC (1.0f / 16.0f)

__device__ __forceinline__ float b2f(short s) {
    union { float f; unsigned u; } c;
    c.u = ((unsigned)(unsigned short)s) << 16;
    return c.f;
}
__device__ __forceinline__ short f2b(float f) {
    union { float f; unsigned u; } c;
    c.f = f;
    unsigned u = c.u;
    unsigned r = (u + 0x7FFFu + ((u >> 16) & 1u)) >> 16;
    return (short)r;
}
__device__ __forceinline__ unsigned f2f8_pk4(float a, float b, float c, float d) {
    int lo = __builtin_amdgcn_cvt_pk_fp8_f32(a, b, 0, false);
    return (unsigned)__builtin_amdgcn_cvt_pk_fp8_f32(c, d, lo, true);
}
__device__ __forceinline__ unsigned char f2f8(float a) {
    return (unsigned char)(__builtin_amdgcn_cvt_pk_fp8_f32(a, a, 0, false) & 0xff);
}

// async global -> LDS, 16 B per lane; lds base must be wave-uniform.
__device__ __forceinline__ void gload16(const void* g, void* l) {
    __builtin_amdgcn_global_load_lds(
        (const __attribute__((address_space(1))) void*)g,
        (__attribute__((address_space(3))) void*)l, 16, 0, 0);
}

// ---------------------------------------------------------------------------
// LayerNorm row helper: fp32 in; OUT8=0 -> bf16 out, OUT8=1 -> fp8 out.
// ---------------------------------------------------------------------------
template <int OUT8>
__device__ __forceinline__ void ln_row(
    const float* __restrict__ x, const float* __restrict__ w,
    const float* __restrict__ bia, void* __restrict__ y,
    int row, int tid, float* red)
{
    const float4 t = *(const float4*)(x + (size_t)row * 1024 + tid * 4);
    float v[4] = {t.x, t.y, t.z, t.w};
    float s = v[0] + v[1] + v[2] + v[3];
    float s2 = v[0]*v[0] + v[1]*v[1] + v[2]*v[2] + v[3]*v[3];
    #pragma unroll
    for (int off = 1; off < 64; off <<= 1) {
        s  += __shfl_xor(s, off);
        s2 += __shfl_xor(s2, off);
    }
    const int wave = tid >> 6, lane = tid & 63;
    if (lane == 0) { red[wave] = s; red[4 + wave] = s2; }
    __syncthreads();
    s  = red[0] + red[1] + red[2] + red[3];
    s2 = red[4] + red[5] + red[6] + red[7];
    const float mu  = s * (1.0f / 1024.0f);
    const float var = s2 * (1.0f / 1024.0f) - mu * mu;
    const float rstd = rsqrtf(var + 1e-6f);
    const float4 wv = *(const float4*)(w + tid * 4);
    const float4 bv = *(const float4*)(bia + tid * 4);
    const float o0 = (v[0] - mu) * rstd * wv.x + bv.x;
    const float o1 = (v[1] - mu) * rstd * wv.y + bv.y;
    const float o2 = (v[2] - mu) * rstd * wv.z + bv.z;
    const float o3 = (v[3] - mu) * rstd * wv.w + bv.w;
    if (OUT8) {
        ((unsigned*)y)[(size_t)row * 256 + tid] = f2f8_pk4(o0, o1, o2, o3);
    } else {
        short4 o;
        o.x = f2b(o0); o.y = f2b(o1); o.z = f2b(o2); o.w = f2b(o3);
        *(short4*)((short*)y + (size_t)row * 1024 + tid * 4) = o;
    }
}

// ---------------------------------------------------------------------------
// prep: q-LN -> bf16 (blocks 0..2047), kv-LN -> fp8 (2048..10239), weight
// casts (10240..22527): Wq,Wo -> bf16; Wkv,fc1,fc2 -> fp8 scaled x16.
// ---------------------------------------------------------------------------
__global__ __launch_bounds__(256) void prep_kernel(
    const float* __restrict__ qt, const float* __restrict__ kvt,
    const float* __restrict__ qlw, const float* __restrict__ qlb,
    const float* __restrict__ klw, const float* __restrict__ klb,
    short* __restrict__ qn, unsigned char* __restrict__ kvn8,
    const float* __restrict__ Wq, const float* __restrict__ Wo,
    const float* __restrict__ Wk, const float* __restrict__ Wv,
    const float* __restrict__ fc1w, const float* __restrict__ fc2w,
    short* __restrict__ Wq_b, short* __restrict__ Wo_b,
    unsigned char* __restrict__ Wkv8,
    unsigned char* __restrict__ fc1_8, unsigned char* __restrict__ fc2_8)
{
    __shared__ float red[8];
    const int bid = blockIdx.x, tid = threadIdx.x;
    if (bid < 2048) {
        ln_row<0>(qt, qlw, qlb, qn, bid, tid, red);
    } else if (bid < 10240) {
        ln_row<1>(kvt, klw, klb, kvn8, bid - 2048, tid, red);
    } else {
        int f = (bid - 10240) * 256 + tid;   // float4 index, total 3145728
        if (f < 524288) {                    // Wq, Wo -> bf16
            const float* src = (f < 262144) ? Wq : Wo;
            short* dst = (f < 262144) ? Wq_b : Wo_b;
            const int off = f & 262143;
            const float4 v = ((const float4*)src)[off];
            short4 o;
            o.x = f2b(v.x); o.y = f2b(v.y); o.z = f2b(v.z); o.w = f2b(v.w);
            ((short4*)dst)[off] = o;
        } else {                             // fp8 x16
            const float* src; unsigned* dst; int off;
            if (f < 1048576) {
                off = f - 524288;
                src = (off < 262144) ? Wk : Wv;
                dst = (unsigned*)Wkv8;
                if (off >= 262144) { src = Wv; }
                const int so = (off < 262144) ? off : off - 262144;
                const float4 v = ((const float4*)src)[so];
                dst[off] = f2f8_pk4(v.x * WSCALE, v.y * WSCALE,
                                    v.z * WSCALE, v.w * WSCALE);
                return;
            } else if (f < 2097152) {
                off = f - 1048576; src = fc1w; dst = (unsigned*)fc1_8;
            } else {
                off = f - 2097152; src = fc2w; dst = (unsigned*)fc2_8;
            }
            const float4 v = ((const float4*)src)[off];
            dst[off] = f2f8_pk4(v.x * WSCALE, v.y * WSCALE,
                                v.z * WSCALE, v.w * WSCALE);
        }
    }
}

// ---------------------------------------------------------------------------
// Standalone LN for MLP: fp32 in, fp8 out.
// ---------------------------------------------------------------------------
__global__ __launch_bounds__(256) void ln8_kernel(
    const float* __restrict__ x, const float* __restrict__ w,
    const float* __restrict__ bia, unsigned char* __restrict__ y)
{
    __shared__ float red[8];
    ln_row<1>(x, w, bia, y, blockIdx.x, threadIdx.x, red);
}

// ---------------------------------------------------------------------------
// bf16 GEMM (small: q-proj, Wo): BN=128, BK=64, dbuf single-barrier K-loop,
// 128 B LDS rows + 3-bit XOR swizzle. Wave tile (BM/2)x64.
// EPI: 1 outF = resF + alpha*(acc+bias); 4 l2norm(64-col head) bf16 out.
// ---------------------------------------------------------------------------
template <int EPI, int BM>
__global__ __launch_bounds__(256) void gemm_bt_kernel(
    const short* __restrict__ A, const short* __restrict__ W,
    int M, int N, int Ks, int Kst,
    const float* __restrict__ bias,
    const float* __restrict__ resF,
    const float* __restrict__ alpha,
    short* __restrict__ out16,
    float* __restrict__ outF)
{
    constexpr int MI = BM / 32;
    __shared__ __attribute__((aligned(16))) short As[2][BM * 64];
    __shared__ __attribute__((aligned(16))) short Bs[2][128 * 64];
    const int bm = blockIdx.y * BM, bn = blockIdx.x * 128;
    const int tid = threadIdx.x;
    const int wave = tid >> 6, lane = tid & 63;
    const int wm = (wave >> 1) * (BM / 2), wn = (wave & 1) * 64;
    const int l15 = lane & 15, quad = lane >> 4;
    const int l7 = l15 & 7;

    f32x4_t acc[MI][4];
    #pragma unroll
    for (int mi = 0; mi < MI; ++mi)
        #pragma unroll
        for (int ni = 0; ni < 4; ++ni)
            acc[mi][ni] = (f32x4_t){0.f, 0.f, 0.f, 0.f};

    auto stage = [&](int buf, int k0) {
        #pragma unroll
        for (int c = 0; c < BM / 32; ++c) {
            const int o = c * 4096 + tid * 16;
            const int row = o >> 7;
            const int g = ((o >> 4) & 7) ^ (row & 7);
            gload16(A + (size_t)(bm + row) * Kst + k0 + g * 8,
                    (char*)As[buf] + c * 4096 + wave * 1024);
        }
        #pragma unroll
        for (int c = 0; c < 4; ++c) {
            const int o = c * 4096 + tid * 16;
            const int row = o >> 7;
            const int g = ((o >> 4) & 7) ^ (row & 7);
            gload16(W + (size_t)(bn + row) * Kst + k0 + g * 8,
                    (char*)Bs[buf] + c * 4096 + wave * 1024);
        }
    };

    const int nIter = Ks >> 6;
    stage(0, 0);
    for (int it = 0; it < nIter; ++it) {
        const int buf = it & 1;
        __syncthreads();
        if (it + 1 < nIter) stage(buf ^ 1, (it + 1) * 64);
        #pragma unroll
        for (int h = 0; h < 2; ++h) {
            const int fg = (((h << 2) | quad) ^ l7) * 8;
            short8_t af[MI], bf[4];
            #pragma unroll
            for (int mi = 0; mi < MI; ++mi)
                af[mi] = *(const short8_t*)&As[buf][(wm + mi * 16 + l15) * 64 + fg];
            #pragma unroll
            for (int ni = 0; ni < 4; ++ni)
                bf[ni] = *(const short8_t*)&Bs[buf][(wn + ni * 16 + l15) * 64 + fg];
            #pragma unroll
            for (int mi = 0; mi < MI; ++mi)
                #pragma unroll
                for (int ni = 0; ni < 4; ++ni)
                    acc[mi][ni] = __builtin_amdgcn_mfma_f32_16x16x32_bf16(
                        af[mi], bf[ni], acc[mi][ni], 0, 0, 0);
        }
    }

    if (EPI == 4) {
        #pragma unroll
        for (int mi = 0; mi < MI; ++mi)
            #pragma unroll
            for (int r = 0; r < 4; ++r) {
                float s = 0.f;
                #pragma unroll
                for (int ni = 0; ni < 4; ++ni) {
                    const float x = acc[mi][ni][r];
                    s += x * x;
                }
                s += __shfl_xor(s, 1); s += __shfl_xor(s, 2);
                s += __shfl_xor(s, 4); s += __shfl_xor(s, 8);
                const float sc = 1.0f / fmaxf(sqrtf(s), 1e-6f);
                #pragma unroll
                for (int ni = 0; ni < 4; ++ni) acc[mi][ni][r] *= sc;
            }
    }

    const float a = (EPI == 1) ? alpha[0] : 0.f;
    #pragma unroll
    for (int mi = 0; mi < MI; ++mi) {
        #pragma unroll
        for (int ni = 0; ni < 4; ++ni) {
            const int n = bn + wn + ni * 16 + l15;
            const float bb = (EPI == 1) ? bias[n] : 0.f;
            #pragma unroll
            for (int r = 0; r < 4; ++r) {
                const int m = bm + wm + mi * 16 + (quad << 2) + r;
                const float x = acc[mi][ni][r];
                if (EPI == 4) {
                    out16[(size_t)m * N + n] = f2b(x);
                } else {
                    const size_t idx = (size_t)m * N + n;
                    outF[idx] = resF[idx] + a * (x + bb);
                }
            }
        }
    }
}

// ---------------------------------------------------------------------------
// fp8 GEMM (big: kv-proj, fc1, fc2): BN=128, BK=128, dbuf single-barrier.
// LDS rows 128 B (128 fp8) with 3-bit XOR swizzle on 16B groups; fragment
// reads are ds_read_b64 (8B) at the b64 4-phase floor. Weights were scaled
// x16 at cast; epilogue multiplies by OSC=1/16 (k-side l2norm is
// scale-invariant; fc2 partials keep the x16, reduce applies OSC).
// EPI: 2 fc1: fp8 out8 = gelu(acc*OSC + bias)
//      7 fc2 split-K partial: outF + z*M*N = acc (raw)
//      8 fused KV: n<1024 -> l2norm -> khd[b,h,kv,d] (out16);
//                  n>=1024 -> acc*OSC -> vhd[b,h,d,kv] ((short*)outF)
// ---------------------------------------------------------------------------
template <int EPI, int BM>
__global__ __launch_bounds__(256) void gemm_f8_kernel(
    const unsigned char* __restrict__ A, const unsigned char* __restrict__ W,
    int M, int N, int Ks, int Kst,
    const float* __restrict__ bias,
    unsigned char* __restrict__ out8,
    short* __restrict__ out16,
    float* __restrict__ outF)
{
    constexpr int MI = BM / 32;
    __shared__ __attribute__((aligned(16))) unsigned char As[2][BM * 128];
    __shared__ __attribute__((aligned(16))) unsigned char Bs[2][128 * 128];
    const int bm = blockIdx.y * BM, bn = blockIdx.x * 128;
    const size_t kbase = (size_t)blockIdx.z * Ks;
    const int tid = threadIdx.x;
    const int wave = tid >> 6, lane = tid & 63;
    const int wm = (wave >> 1) * (BM / 2), wn = (wave & 1) * 64;
    const int l15 = lane & 15, quad = lane >> 4;
    const int l7 = l15 & 7;

    f32x4_t acc[MI][4];
    #pragma unroll
    for (int mi = 0; mi < MI; ++mi)
        #pragma unroll
        for (int ni = 0; ni < 4; ++ni)
            acc[mi][ni] = (f32x4_t){0.f, 0.f, 0.f, 0.f};

    auto stage = [&](int buf, int k0) {
        #pragma unroll
        for (int c = 0; c < BM / 32; ++c) {       // A: BM rows x 128 B
            const int o = c * 4096 + tid * 16;
            const int row = o >> 7;
            const int g = ((o >> 4) & 7) ^ (row & 7);
            gload16(A + (size_t)(bm + row) * Kst + kbase + k0 + g * 16,
                    (char*)As[buf] + c * 4096 + wave * 1024);
        }
        #pragma unroll
        for (int c = 0; c < 4; ++c) {             // B: 128 rows x 128 B
            const int o = c * 4096 + tid * 16;
            const int row = o >> 7;
            const int g = ((o >> 4) & 7) ^ (row & 7);
            gload16(W + (size_t)(bn + row) * Kst + kbase + k0 + g * 16,
                    (char*)Bs[buf] + c * 4096 + wave * 1024);
        }
    };

    const int nIter = Ks >> 7;
    stage(0, 0);
    for (int it = 0; it < nIter; ++it) {
        const int buf = it & 1;
        __syncthreads();   // drains stage(it); prev compute done with buf^1
        if (it + 1 < nIter) stage(buf ^ 1, (it + 1) * 128);
        #pragma unroll
        for (int ks = 0; ks < 4; ++ks) {
            const int fo = ((((ks << 1) | (quad >> 1)) ^ l7) << 4) + (quad & 1) * 8;
            long af[MI], bf[4];
            #pragma unroll
            for (int mi = 0; mi < MI; ++mi)
                af[mi] = *(const long*)&As[buf][(wm + mi * 16 + l15) * 128 + fo];
            #pragma unroll
            for (int ni = 0; ni < 4; ++ni)
                bf[ni] = *(const long*)&Bs[buf][(wn + ni * 16 + l15) * 128 + fo];
            #pragma unroll
            for (int mi = 0; mi < MI; ++mi)
                #pragma unroll
                for (int ni = 0; ni < 4; ++ni)
                    acc[mi][ni] = __builtin_amdgcn_mfma_f32_16x16x32_fp8_fp8(
                        af[mi], bf[ni], acc[mi][ni], 0, 0, 0);
        }
    }

    // ---- epilogue ----
    if (EPI == 8 && (bn + wn) < 1024) {   // l2norm (scale-invariant) for k
        #pragma unroll
        for (int mi = 0; mi < MI; ++mi)
            #pragma unroll
            for (int r = 0; r < 4; ++r) {
                float s = 0.f;
                #pragma unroll
                for (int ni = 0; ni < 4; ++ni) {
                    const float x = acc[mi][ni][r];
                    s += x * x;
                }
                s += __shfl_xor(s, 1); s += __shfl_xor(s, 2);
                s += __shfl_xor(s, 4); s += __shfl_xor(s, 8);
                const float sc = 1.0f / fmaxf(sqrtf(s), 1e-6f);
                #pragma unroll
                for (int ni = 0; ni < 4; ++ni) acc[mi][ni][r] *= sc;
            }
    }

    #pragma unroll
    for (int mi = 0; mi < MI; ++mi) {
        #pragma unroll
        for (int ni = 0; ni < 4; ++ni) {
            const int n = bn + wn + ni * 16 + l15;
            const float bb = (EPI == 2) ? bias[n] : 0.f;
            #pragma unroll
            for (int r = 0; r < 4; ++r) {
                const int m = bm + wm + mi * 16 + (quad << 2) + r;
                const float x = acc[mi][ni][r];
                if (EPI == 2) {
                    const float t = x * OSC + bb;
                    out8[(size_t)m * N + n] =
                        f2f8(0.5f * t * (1.0f + erff(t * 0.70710678118f)));
                } else if (EPI == 7) {
                    outF[(size_t)blockIdx.z * M * N + (size_t)m * N + n] = x;
                } else if (EPI == 8) {
                    if (n < 1024) {       // khd[b,h,kv,d]
                        out16[(size_t)(((m >> 11) * 16 + (n >> 6)) * 2048 +
                                       (m & 2047)) * 64 + (n & 63)] = f2b(x);
                    } else {              // vhd[b,h,d,kv]
                        const int nn = n - 1024;
                        ((short*)outF)[(size_t)(((m >> 11) * 16 + (nn >> 6)) * 64 +
                                       (nn & 63)) * 2048 + (m & 2047)] =
                            f2b(x * OSC);
                    }
                }
            }
        }
    }
}

// ---------------------------------------------------------------------------
// Split-K reduce for fc2: out = resF + alpha*((p0+p1+p2+p3)*OSC + bias).
// ---------------------------------------------------------------------------
__global__ __launch_bounds__(256) void reduce4_kernel(
    const float* __restrict__ parts, const float* __restrict__ resF,
    const float* __restrict__ bias, const float* __restrict__ alpha,
    float* __restrict__ out)
{
    const int i = blockIdx.x * 256 + threadIdx.x;   // float4 index over 2048x1024
    const size_t MN4 = (size_t)2048 * 1024 / 4;
    const float a = alpha[0];
    const float4 b4 = ((const float4*)bias)[i & 255];
    float4 s = ((const float4*)parts)[i];
    const float4 p1 = ((const float4*)parts)[MN4 + i];
    const float4 p2 = ((const float4*)parts)[2 * MN4 + i];
    const float4 p3 = ((const float4*)parts)[3 * MN4 + i];
    const float4 rv = ((const float4*)resF)[i];
    float4 o;
    o.x = rv.x + a * ((s.x + p1.x + p2.x + p3.x) * OSC + b4.x);
    o.y = rv.y + a * ((s.y + p1.y + p2.y + p3.y) * OSC + b4.y);
    o.z = rv.z + a * ((s.z + p1.z + p2.z + p3.z) * OSC + b4.z);
    o.w = rv.w + a * ((s.w + p1.w + p2.w + p3.w) * OSC + b4.w);
    ((float4*)out)[i] = o;
}

// ---------------------------------------------------------------------------
// Attention (r5 version): block = (q-tile 64, head, batch) = 512 blocks;
// 4 waves x 16 Q rows. K/V tiles staged via global_load_lds, double-buffered,
// 1 barrier/tile, 128 B LDS rows + 3-bit row XOR (conflict-free b128).
// No running max needed: |q.k| <= 1 after l2norm.
// ---------------------------------------------------------------------------
__global__ __launch_bounds__(256) void attn_kernel(
    const short* __restrict__ q, const short* __restrict__ khd,
    const short* __restrict__ vhd, short* __restrict__ ctx)
{
    const int qt = blockIdx.x;   // 0..7
    const int h  = blockIdx.y;   // 0..15
    const int b  = blockIdx.z;   // 0..3
    const int tid = threadIdx.x;
    const int wave = tid >> 6, lane = tid & 63;
    const int l15 = lane & 15, quad = lane >> 4;
    const int q0 = qt * 64 + wave * 16;

    __shared__ __attribute__((aligned(16))) short Ks[2][4096];
    __shared__ __attribute__((aligned(16))) short Vs[2][4096];
    __shared__ __attribute__((aligned(16))) short P[4][1152];   // 16 x 72

    const short* qbase = q + (size_t)(b * 512 + q0 + l15) * 1024 + h * 64 + quad * 8;
    const short8_t aq0 = *(const short8_t*)(qbase);
    const short8_t aq1 = *(const short8_t*)(qbase + 32);

    const short* kbase = khd + (size_t)(b * 16 + h) * 2048 * 64;  // [2048][64]
    const short* vbase = vhd + (size_t)(b * 16 + h) * 64 * 2048;  // [64][2048]

    const int swz = l15 & 7;
    const int g0 = (quad ^ swz) * 8;
    const int g1 = ((quad ^ swz) ^ 4) * 8;

    auto stage = [&](int buf, int t) {
        #pragma unroll
        for (int c = 0; c < 2; ++c) {
            const int o = c * 4096 + tid * 16;
            const int row = o >> 7;              // 64 rows x 128 B
            const int g = ((o >> 4) & 7) ^ (row & 7);
            gload16(kbase + (size_t)(t * 64 + row) * 64 + g * 8,
                    (char*)Ks[buf] + c * 4096 + wave * 1024);
            gload16(vbase + (size_t)row * 2048 + t * 64 + g * 8,
                    (char*)Vs[buf] + c * 4096 + wave * 1024);
        }
    };

    f32x4_t oacc[4];
    #pragma unroll
    for (int u = 0; u < 4; ++u) oacc[u] = (f32x4_t){0.f, 0.f, 0.f, 0.f};
    float l[4] = {0.f, 0.f, 0.f, 0.f};

    stage(0, 0);
    for (int t = 0; t < 32; ++t) {
        const int buf = t & 1;
        __syncthreads();
        if (t + 1 < 32) stage(buf ^ 1, t + 1);

        f32x4_t s[4];
        #pragma unroll
        for (int ss = 0; ss < 4; ++ss) {
            const int R = ss * 16 + l15;
            const short8_t bk0 = *(const short8_t*)&Ks[buf][R * 64 + g0];
            const short8_t bk1 = *(const short8_t*)&Ks[buf][R * 64 + g1];
            f32x4_t a = (f32x4_t){0.f, 0.f, 0.f, 0.f};
            a = __builtin_amdgcn_mfma_f32_16x16x32_bf16(aq0, bk0, a, 0, 0, 0);
            a = __builtin_amdgcn_mfma_f32_16x16x32_bf16(aq1, bk1, a, 0, 0, 0);
            s[ss] = a;
        }
        float rs[4] = {0.f, 0.f, 0.f, 0.f};
        #pragma unroll
        for (int ss = 0; ss < 4; ++ss)
            #pragma unroll
            for (int r = 0; r < 4; ++r) {
                const float p = __expf(s[ss][r] * 0.5f);
                s[ss][r] = p;
                rs[r] += p;
            }
        #pragma unroll
        for (int r = 0; r < 4; ++r) {
            float v = rs[r];
            v += __shfl_xor(v, 1); v += __shfl_xor(v, 2);
            v += __shfl_xor(v, 4); v += __shfl_xor(v, 8);
            l[r] += v;
        }
        #pragma unroll
        for (int ss = 0; ss < 4; ++ss)
            #pragma unroll
            for (int r = 0; r < 4; ++r)
                P[wave][(quad * 4 + r) * 72 + ss * 16 + l15] = f2b(s[ss][r]);
        const short8_t ap0 = *(const short8_t*)&P[wave][l15 * 72 + quad * 8];
        const short8_t ap1 = *(const short8_t*)&P[wave][l15 * 72 + 32 + quad * 8];
        #pragma unroll
        for (int u = 0; u < 4; ++u) {
            const int R = u * 16 + l15;
            const short8_t bv0 = *(const short8_t*)&Vs[buf][R * 64 + g0];
            const short8_t bv1 = *(const short8_t*)&Vs[buf][R * 64 + g1];
            oacc[u] = __builtin_amdgcn_mfma_f32_16x16x32_bf16(ap0, bv0, oacc[u], 0, 0, 0);
            oacc[u] = __builtin_amdgcn_mfma_f32_16x16x32_bf16(ap1, bv1, oacc[u], 0, 0, 0);
        }
    }
    #pragma unroll
    for (int u = 0; u < 4; ++u)
        #pragma unroll
        for (int r = 0; r < 4; ++r) {
            const float val = oacc[u][r] / l[r];
            ctx[(size_t)(b * 512 + q0 + quad * 4 + r) * 1024 + h * 64 + u * 16 + l15] =
                f2b(val);
        }
}

// ---------------------------------------------------------------------------
extern "C" void kernel_launch(void* const* d_in, const int* in_sizes, int n_in,
                              void* d_out, int out_size, void* d_ws, size_t ws_size,
                              hipStream_t stream)
{
    const float* q_tokens  = (const float*)d_in[0];
    const float* kv_tokens = (const float*)d_in[1];
    const float* q_ln_w    = (const float*)d_in[2];
    const float* q_ln_b    = (const float*)d_in[3];
    const float* kv_ln_w   = (const float*)d_in[4];
    const float* kv_ln_b   = (const float*)d_in[5];
    const float* mlp_ln_w  = (const float*)d_in[6];
    const float* mlp_ln_b  = (const float*)d_in[7];
    const float* Wq        = (const float*)d_in[8];
    const float* Wk        = (const float*)d_in[9];
    const float* Wv        = (const float*)d_in[10];
    const float* Wo        = (const float*)d_in[11];
    const float* bo        = (const float*)d_in[12];
    const float* fc1_w     = (const float*)d_in[13];
    const float* fc1_b     = (const float*)d_in[14];
    const float* fc2_w     = (const float*)d_in[15];
    const float* fc2_b     = (const float*)d_in[16];
    const float* alpha_attn = (const float*)d_in[17];
    const float* alpha_mlp  = (const float*)d_in[18];

    char* ws = (char*)d_ws;
    const size_t MB = (size_t)1 << 20;
    short* khd    = (short*)(ws);             // 16 MB [4,16,2048,64]; dead after attn
    short* vhd    = (short*)(ws + 16 * MB);   // 16 MB [4,16,64,2048]; dead after attn
    float* parts  = (float*)(ws);             // 32 MB fc2 partials (overlays khd+vhd)
    unsigned char* kvn8 = (unsigned char*)(ws + 32 * MB); // 8 MB; dead after kv-gemm
    unsigned char* h1   = (unsigned char*)(ws + 32 * MB); //    overlays kvn8: 8 MB fp8
    short* qn     = (short*)(ws + 40 * MB);   //  4 MB [2048,1024] bf16
    short* qbuf   = (short*)(ws + 44 * MB);   //  4 MB [2048,1024] bf16 (l2-normed q)
    short* ctx    = (short*)(ws + 48 * MB);   //  4 MB [2048,1024] bf16
    float* aout   = (float*)(ws + 52 * MB);   //  8 MB [2048,1024] fp32
    unsigned char* hn8 = (unsigned char*)(ws + 60 * MB);  // 2 MB fp8
    short* Wq_b   = (short*)(ws + 62 * MB);   //  2 MB bf16
    short* Wo_b   = (short*)(ws + 64 * MB);   //  2 MB bf16
    unsigned char* Wkv8  = (unsigned char*)(ws + 66 * MB); // 2 MB fp8 stacked
    unsigned char* fc1_8 = (unsigned char*)(ws + 68 * MB); // 4 MB fp8
    unsigned char* fc2_8 = (unsigned char*)(ws + 72 * MB); // 4 MB fp8

    // 0) fused: q-LN(bf16) + kv-LN(fp8) + weight casts
    prep_kernel<<<22528, 256, 0, stream>>>(
        q_tokens, kv_tokens, q_ln_w, q_ln_b, kv_ln_w, kv_ln_b, qn, kvn8,
        Wq, Wo, Wk, Wv, fc1_w, fc2_w,
        Wq_b, Wo_b, Wkv8, fc1_8, fc2_8);

    // 1) q-proj (+l2norm, bf16) and fused kv-proj (fp8, l2norm/scatter)
    gemm_bt_kernel<4, 64><<<dim3(8, 32), 256, 0, stream>>>(
        qn, Wq_b, 2048, 1024, 1024, 1024, nullptr, nullptr, nullptr, qbuf, nullptr);
    gemm_f8_kernel<8, 128><<<dim3(16, 64), 256, 0, stream>>>(
        kvn8, Wkv8, 8192, 2048, 1024, 1024, nullptr, nullptr, khd, (float*)vhd);

    // 2) Attention (q-tile 64, 512 blocks)
    attn_kernel<<<dim3(8, 16, 4), 256, 0, stream>>>(qbuf, khd, vhd, ctx);

    // 3) Out-proj + residual (bf16): aout = q_tokens + alpha*(ctx@Wo^T + bo)
    gemm_bt_kernel<1, 64><<<dim3(8, 32), 256, 0, stream>>>(
        ctx, Wo_b, 2048, 1024, 1024, 1024, bo, q_tokens, alpha_attn, nullptr, aout);

    // 4) MLP LN -> fp8
    ln8_kernel<<<2048, 256, 0, stream>>>(aout, mlp_ln_w, mlp_ln_b, hn8);

    // 5) fc1 (fp8) + exact GELU -> fp8 h1
    gemm_f8_kernel<2, 128><<<dim3(32, 16), 256, 0, stream>>>(
        hn8, fc1_8, 2048, 4096, 1024, 1024, fc1_b, h1, nullptr, nullptr);

    // 6) fc2 (fp8) split-K x4 -> fp32 partials, reduce + residual -> d_out
    gemm_f8_kernel<7, 64><<<dim3(8, 32, 4), 256, 0, stream>>>(
        h1, fc2_8, 2048, 1024, 1024, 4096, nullptr, nullptr, nullptr, parts);
    reduce4_kernel<<<2048, 256, 0, stream>>>(parts, aout, fc2_b, alpha_mlp,
                                             (float*)d_out);
}